// Round 16
// baseline (188.104 us; speedup 1.0000x reference)
//
#include <hip/hip_runtime.h>
#include <hip/hip_fp16.h>

#define L_SEQ 1024
#define NB 32
#define NH 8
#define NE 64
#define TOPK 6

typedef unsigned int u32;

// LDS geometry (round 16): TWO fp16x2-packed 8-plane tile buffers (double
// buffer) + fp32 twiddle table. Plane: 1024 packed complex (u32), 32 groups
// of 32 at stride 36. 2*8*1152*4 + 544*4 = 75,904 B -> 2 blocks/CU.
// Pipelining rationale: rounds 7-15 all land ~150-160us with NO resource
// saturated (VALU 35%, HBM 16%, LDS ~50%) -> phase serialization. This round
// overlaps tile i+1's HBM traffic (issued into regs) with tile i's compute.
#define PSC  1152                 // u32 per packed series plane
#define NPL  8                    // planes (series) per buffer
#define BUFU (NPL * PSC)          // 9216 u32 per buffer
#define TBOU (2 * BUFU)           // table offset (u32 units)
#define PHYS(L)  (36 * ((L) >> 5) + ((L) & 31))
#define TPHYS(E) ((E) + ((E) >> 4))
#define LDS_BYTES ((TBOU + 544) * 4)   // 75,904 B

constexpr float K16C[4] = {1.f, 0.92387953f, 0.70710678f, 0.38268343f};
constexpr float K16S[4] = {0.f, 0.38268343f, 0.70710678f, 0.92387953f};

__device__ __forceinline__ u32 PK(float r, float i) {
    union { __half2 h; u32 u; } c;
    c.h = __floats2half2_rn(r, i);
    return c.u;
}
__device__ __forceinline__ float2 UPK(u32 u) {
    union { u32 u; __half2 h; } c;
    c.u = u;
    return __half22float2(c.h);
}
#define UQ4(Z,R,I) { const float2 a_=UPK(Z.x), b_=UPK(Z.y), c_=UPK(Z.z), d_=UPK(Z.w); \
    R = make_float4(a_.x,b_.x,c_.x,d_.x); I = make_float4(a_.y,b_.y,c_.y,d_.y); }
#define PQ4(Z,R,I) { Z.x=PK(R.x,I.x); Z.y=PK(R.y,I.y); Z.z=PK(R.z,I.z); Z.w=PK(R.w,I.w); }

#define BTF4F(A,B,C,D) { \
    const float t0r = xr##A + xr##C, t0i = xi##A + xi##C; \
    const float d2r = xr##A - xr##C, d2i = xi##A - xi##C; \
    const float t2r = d2r*w1r - d2i*w1i, t2i = d2i*w1r + d2r*w1i; \
    const float t1r = xr##B + xr##D, t1i = xi##B + xi##D; \
    const float d3r = xr##B - xr##D, d3i = xi##B - xi##D; \
    const float m3r = d3r*w1r - d3i*w1i, m3i = d3i*w1r + d3r*w1i; \
    const float t3r = m3i, t3i = -m3r; \
    const float a0r = t0r + t1r, a0i = t0i + t1i; \
    const float a1r = t0r - t1r, a1i = t0i - t1i; \
    const float a2r = t2r + t3r, a2i = t2i + t3i; \
    const float a3r = t2r - t3r, a3i = t2i - t3i; \
    xr##A = a0r; xi##A = a0i; \
    xr##B = a1r*w3r - a1i*w3i; xi##B = a1i*w3r + a1r*w3i; \
    xr##C = a2r; xi##C = a2i; \
    xr##D = a3r*w3r - a3i*w3i; xi##D = a3i*w3r + a3r*w3i; }

#define BTF4I(A,B,C,D) { \
    const float m1r = xr##B*w3r - xi##B*w3i, m1i = xi##B*w3r + xr##B*w3i; \
    const float s0r = xr##A + m1r, s0i = xi##A + m1i; \
    const float s1r = xr##A - m1r, s1i = xi##A - m1i; \
    const float m3r = xr##D*w3r - xi##D*w3i, m3i = xi##D*w3r + xr##D*w3i; \
    const float s2r = xr##C + m3r, s2i = xi##C + m3i; \
    const float s3r = xr##C - m3r, s3i = xi##C - m3i; \
    const float t2r = s2r*w1r - s2i*w1i, t2i = s2i*w1r + s2r*w1i; \
    const float n3r = s3r*w1r - s3i*w1i, n3i = s3i*w1r + s3r*w1i; \
    const float t3r = -n3i, t3i = n3r; \
    xr##A = s0r + t2r; xi##A = s0i + t2i; \
    xr##C = s0r - t2r; xi##C = s0i - t2i; \
    xr##B = s1r + t3r; xi##B = s1i + t3i; \
    xr##D = s1r - t3r; xi##D = s1i - t3i; }

// ---- head4: levels 1024,512,256,128 in one pass; lane owns {lane + 64j}.
__device__ __forceinline__ void head4_fwd(u32* __restrict__ pc,
                                          const float* __restrict__ tab, int lane)
{
    const int A0 = 36 * (lane >> 5) + (lane & 31);
    const float tc = tab[TPHYS(lane)];
    const float ts = tab[272 + TPHYS(lane)];
    const float wbr = tc, wbi = -ts;
    const float w2r = wbr*wbr - wbi*wbi, w2i = 2.f*wbr*wbi;
    const float w4r = w2r*w2r - w2i*w2i, w4i = 2.f*w2r*w2i;
    const float w8r = w4r*w4r - w4i*w4i, w8i = 2.f*w4r*w4i;
#define HD(J) float xr##J, xi##J; { const float2 z_ = UPK(pc[A0 + 72*J]); xr##J = z_.x; xi##J = z_.y; }
    HD(0) HD(1) HD(2) HD(3) HD(4) HD(5) HD(6) HD(7)
    HD(8) HD(9) HD(10) HD(11) HD(12) HD(13) HD(14) HD(15)
#undef HD
#define STA(JA,JB,JC,JD,J16) { \
    const float w1r = wbr*K16C[J16] + wbi*K16S[J16]; \
    const float w1i = wbi*K16C[J16] - wbr*K16S[J16]; \
    const float w3r = w1r*w1r - w1i*w1i, w3i = 2.f*w1r*w1i; \
    BTF4F(JA,JB,JC,JD) }
    STA(0,4,8,12,0) STA(1,5,9,13,1) STA(2,6,10,14,2) STA(3,7,11,15,3)
#undef STA
    {
        const float w1r = w4r, w1i = w4i, w3r = w8r, w3i = w8i;
        BTF4F(0,1,2,3) BTF4F(4,5,6,7) BTF4F(8,9,10,11) BTF4F(12,13,14,15)
    }
#define HS(J) pc[A0 + 72*J] = PK(xr##J, xi##J);
    HS(0) HS(1) HS(2) HS(3) HS(4) HS(5) HS(6) HS(7)
    HS(8) HS(9) HS(10) HS(11) HS(12) HS(13) HS(14) HS(15)
#undef HS
}

__device__ __forceinline__ void head4_inv(u32* __restrict__ pc,
                                          const float* __restrict__ tab, int lane)
{
    const int A0 = 36 * (lane >> 5) + (lane & 31);
    const float tc = tab[TPHYS(lane)];
    const float ts = tab[272 + TPHYS(lane)];
    const float vbr = tc, vbi = ts;
    const float v2r = vbr*vbr - vbi*vbi, v2i = 2.f*vbr*vbi;
    const float v4r = v2r*v2r - v2i*v2i, v4i = 2.f*v2r*v2i;
    const float v8r = v4r*v4r - v4i*v4i, v8i = 2.f*v4r*v4i;
#define HD(J) float xr##J, xi##J; { const float2 z_ = UPK(pc[A0 + 72*J]); xr##J = z_.x; xi##J = z_.y; }
    HD(0) HD(1) HD(2) HD(3) HD(4) HD(5) HD(6) HD(7)
    HD(8) HD(9) HD(10) HD(11) HD(12) HD(13) HD(14) HD(15)
#undef HD
    {
        const float w1r = v4r, w1i = v4i, w3r = v8r, w3i = v8i;
        BTF4I(0,1,2,3) BTF4I(4,5,6,7) BTF4I(8,9,10,11) BTF4I(12,13,14,15)
    }
#define STB(JA,JB,JC,JD,J16) { \
    const float w1r = vbr*K16C[J16] - vbi*K16S[J16]; \
    const float w1i = vbi*K16C[J16] + vbr*K16S[J16]; \
    const float w3r = w1r*w1r - w1i*w1i, w3i = 2.f*w1r*w1i; \
    BTF4I(JA,JB,JC,JD) }
    STB(0,4,8,12,0) STB(1,5,9,13,1) STB(2,6,10,14,2) STB(3,7,11,15,3)
#undef STB
#define HS(J) pc[A0 + 72*J] = PK(xr##J, xi##J);
    HS(0) HS(1) HS(2) HS(3) HS(4) HS(5) HS(6) HS(7)
    HS(8) HS(9) HS(10) HS(11) HS(12) HS(13) HS(14) HS(15)
#undef HS
}

// ---- mid stage (levels 64,32): packed-quad radix-4
__device__ __forceinline__ void dif_mid(u32* __restrict__ pc,
                                        const float* __restrict__ tab, int lane)
{
    const int b0 = lane << 2;
    const int u0 = b0 & 15;
    const int Lb = ((b0 >> 4) << 6) + u0;
    const int P0 = PHYS(Lb), P1 = PHYS(Lb + 16), P2 = PHYS(Lb + 32), P3 = PHYS(Lb + 48);
    uint4 z0 = *(const uint4*)(pc + P0), z1 = *(const uint4*)(pc + P1);
    uint4 z2 = *(const uint4*)(pc + P2), z3 = *(const uint4*)(pc + P3);
    float4 r0, i0, r1, i1, r2, i2, r3, i3;
    UQ4(z0, r0, i0) UQ4(z1, r1, i1) UQ4(z2, r2, i2) UQ4(z3, r3, i3)
#define CBTF(CMP, II) { \
    const int e1 = (u0 + II) << 4; \
    const float w1c = tab[TPHYS(e1)]; \
    const float w1s = tab[272 + TPHYS(e1)]; \
    const float w3c = w1c * w1c - w1s * w1s; \
    const float w3s = 2.f * w1c * w1s; \
    const float t0r = r0.CMP + r2.CMP, t0i = i0.CMP + i2.CMP; \
    const float d2r = r0.CMP - r2.CMP, d2i = i0.CMP - i2.CMP; \
    const float t2r = d2r * w1c + d2i * w1s, t2i = d2i * w1c - d2r * w1s; \
    const float t1r = r1.CMP + r3.CMP, t1i = i1.CMP + i3.CMP; \
    const float d3r = r1.CMP - r3.CMP, d3i = i1.CMP - i3.CMP; \
    const float m3r = d3r * w1c + d3i * w1s, m3i = d3i * w1c - d3r * w1s; \
    const float t3r = m3i, t3i = -m3r; \
    const float a0r = t0r + t1r, a0i = t0i + t1i; \
    const float a1r = t0r - t1r, a1i = t0i - t1i; \
    const float a2r = t2r + t3r, a2i = t2i + t3i; \
    const float a3r = t2r - t3r, a3i = t2i - t3i; \
    r0.CMP = a0r;                     i0.CMP = a0i; \
    r1.CMP = a1r * w3c + a1i * w3s;   i1.CMP = a1i * w3c - a1r * w3s; \
    r2.CMP = a2r;                     i2.CMP = a2i; \
    r3.CMP = a3r * w3c + a3i * w3s;   i3.CMP = a3i * w3c - a3r * w3s; }
    CBTF(x, 0) CBTF(y, 1) CBTF(z, 2) CBTF(w, 3)
#undef CBTF
    PQ4(z0, r0, i0) PQ4(z1, r1, i1) PQ4(z2, r2, i2) PQ4(z3, r3, i3)
    *(uint4*)(pc + P0) = z0; *(uint4*)(pc + P1) = z1;
    *(uint4*)(pc + P2) = z2; *(uint4*)(pc + P3) = z3;
}

__device__ __forceinline__ void dit_mid(u32* __restrict__ pc,
                                        const float* __restrict__ tab, int lane)
{
    const int b0 = lane << 2;
    const int u0 = b0 & 15;
    const int Lb = ((b0 >> 4) << 6) + u0;
    const int P0 = PHYS(Lb), P1 = PHYS(Lb + 16), P2 = PHYS(Lb + 32), P3 = PHYS(Lb + 48);
    uint4 z0 = *(const uint4*)(pc + P0), z1 = *(const uint4*)(pc + P1);
    uint4 z2 = *(const uint4*)(pc + P2), z3 = *(const uint4*)(pc + P3);
    float4 r0, i0, r1, i1, r2, i2, r3, i3;
    UQ4(z0, r0, i0) UQ4(z1, r1, i1) UQ4(z2, r2, i2) UQ4(z3, r3, i3)
#define CBTI(CMP, II) { \
    const int e1 = (u0 + II) << 4; \
    const float w1c = tab[TPHYS(e1)]; \
    const float w1s = tab[272 + TPHYS(e1)]; \
    const float w3c = w1c * w1c - w1s * w1s; \
    const float w3s = 2.f * w1c * w1s; \
    const float m1r = r1.CMP * w3c - i1.CMP * w3s, m1i = i1.CMP * w3c + r1.CMP * w3s; \
    const float s0r = r0.CMP + m1r, s0i = i0.CMP + m1i; \
    const float s1r = r0.CMP - m1r, s1i = i0.CMP - m1i; \
    const float m3r = r3.CMP * w3c - i3.CMP * w3s, m3i = i3.CMP * w3c + r3.CMP * w3s; \
    const float s2r = r2.CMP + m3r, s2i = i2.CMP + m3i; \
    const float s3r = r2.CMP - m3r, s3i = i2.CMP - m3i; \
    const float p2r = s2r * w1c - s2i * w1s, p2i = s2i * w1c + s2r * w1s; \
    const float n3r = s3r * w1c - s3i * w1s, n3i = s3i * w1c + s3r * w1s; \
    const float p3r = -n3i, p3i = n3r; \
    r0.CMP = s0r + p2r; i0.CMP = s0i + p2i; \
    r2.CMP = s0r - p2r; i2.CMP = s0i - p2i; \
    r1.CMP = s1r + p3r; i1.CMP = s1i + p3i; \
    r3.CMP = s1r - p3r; i3.CMP = s1i - p3i; }
    CBTI(x, 0) CBTI(y, 1) CBTI(z, 2) CBTI(w, 3)
#undef CBTI
    PQ4(z0, r0, i0) PQ4(z1, r1, i1) PQ4(z2, r2, i2) PQ4(z3, r3, i3)
    *(uint4*)(pc + P0) = z0; *(uint4*)(pc + P1) = z1;
    *(uint4*)(pc + P2) = z2; *(uint4*)(pc + P3) = z3;
}

// ---- tail_fused: levels 16..2 | S=Q*conj(K)/1024 | levels 2..16, one trip.
__device__ __forceinline__ void tail_fused(u32* __restrict__ pc, int lane)
{
    const int Pb = PHYS(lane << 4);
    uint4 z0 = *(const uint4*)(pc + Pb),     z1 = *(const uint4*)(pc + Pb + 4);
    uint4 z2 = *(const uint4*)(pc + Pb + 8), z3 = *(const uint4*)(pc + Pb + 12);
    float4 r0, i0, r1, i1, r2, i2, r3, i3;
    UQ4(z0, r0, i0) UQ4(z1, r1, i1) UQ4(z2, r2, i2) UQ4(z3, r3, i3)
#define TCF(CMP, C) { \
    const float w1r = K16C[C], w1i = -K16S[C]; \
    const float w3r = w1r*w1r - w1i*w1i, w3i = 2.f*w1r*w1i; \
    const float t0r = r0.CMP + r2.CMP, t0i = i0.CMP + i2.CMP; \
    const float d2r = r0.CMP - r2.CMP, d2i = i0.CMP - i2.CMP; \
    const float t2r = d2r*w1r - d2i*w1i, t2i = d2i*w1r + d2r*w1i; \
    const float t1r = r1.CMP + r3.CMP, t1i = i1.CMP + i3.CMP; \
    const float d3r = r1.CMP - r3.CMP, d3i = i1.CMP - i3.CMP; \
    const float m3r = d3r*w1r - d3i*w1i, m3i = d3i*w1r + d3r*w1i; \
    const float t3r = m3i, t3i = -m3r; \
    const float a0r = t0r+t1r, a0i = t0i+t1i; \
    const float a1r = t0r-t1r, a1i = t0i-t1i; \
    const float a2r = t2r+t3r, a2i = t2i+t3i; \
    const float a3r = t2r-t3r, a3i = t2i-t3i; \
    r0.CMP = a0r; i0.CMP = a0i; \
    r1.CMP = a1r*w3r - a1i*w3i; i1.CMP = a1i*w3r + a1r*w3i; \
    r2.CMP = a2r; i2.CMP = a2i; \
    r3.CMP = a3r*w3r - a3i*w3i; i3.CMP = a3i*w3r + a3r*w3i; }
    TCF(x,0) TCF(y,1) TCF(z,2) TCF(w,3)
#undef TCF
#define Q4F(RQ, IQ) { \
    const float t0r = RQ.x + RQ.z, t0i = IQ.x + IQ.z; \
    const float t2r = RQ.x - RQ.z, t2i = IQ.x - IQ.z; \
    const float t1r = RQ.y + RQ.w, t1i = IQ.y + IQ.w; \
    const float d3r = RQ.y - RQ.w, d3i = IQ.y - IQ.w; \
    const float t3r = d3i, t3i = -d3r; \
    RQ.x = t0r + t1r; IQ.x = t0i + t1i; \
    RQ.y = t0r - t1r; IQ.y = t0i - t1i; \
    RQ.z = t2r + t3r; IQ.z = t2i + t3i; \
    RQ.w = t2r - t3r; IQ.w = t2i - t3i; }
    Q4F(r0, i0) Q4F(r1, i1) Q4F(r2, i2) Q4F(r3, i3)
#undef Q4F
    PQ4(z0, r0, i0) PQ4(z1, r1, i1) PQ4(z2, r2, i2) PQ4(z3, r3, i3)
    *(uint4*)(pc + Pb) = z0;     *(uint4*)(pc + Pb + 4) = z1;
    *(uint4*)(pc + Pb + 8) = z2; *(uint4*)(pc + Pb + 12) = z3;
#define UNP(RQ, IQ, QI, CMP, JJ) { \
    const int p  = (lane << 4) + 4*QI + JJ; \
    const int f  = (int)(__brev((unsigned)p) >> 22); \
    const int fb = (1024 - f) & 1023; \
    const int pb = (int)(__brev((unsigned)fb) >> 22); \
    const float2 b_ = UPK(pc[PHYS(pb)]); \
    const float arv = RQ.CMP, aiv = IQ.CMP; \
    const float Qr = 0.5f*(arv + b_.x), Qi = 0.5f*(aiv - b_.y); \
    const float Kr = 0.5f*(aiv + b_.y), Ki = 0.5f*(b_.x - arv); \
    RQ.CMP = (Qr*Kr + Qi*Ki) * (1.f/1024.f); \
    IQ.CMP = (Qi*Kr - Qr*Ki) * (1.f/1024.f); }
    UNP(r0,i0,0,x,0) UNP(r0,i0,0,y,1) UNP(r0,i0,0,z,2) UNP(r0,i0,0,w,3)
    UNP(r1,i1,1,x,0) UNP(r1,i1,1,y,1) UNP(r1,i1,1,z,2) UNP(r1,i1,1,w,3)
    UNP(r2,i2,2,x,0) UNP(r2,i2,2,y,1) UNP(r2,i2,2,z,2) UNP(r2,i2,2,w,3)
    UNP(r3,i3,3,x,0) UNP(r3,i3,3,y,1) UNP(r3,i3,3,z,2) UNP(r3,i3,3,w,3)
#undef UNP
#define Q4I(RQ, IQ) { \
    const float s0r = RQ.x + RQ.y, s0i = IQ.x + IQ.y; \
    const float s1r = RQ.x - RQ.y, s1i = IQ.x - IQ.y; \
    const float s2r = RQ.z + RQ.w, s2i = IQ.z + IQ.w; \
    const float s3r = RQ.z - RQ.w, s3i = IQ.z - IQ.w; \
    const float p3r = -s3i, p3i = s3r; \
    RQ.x = s0r + s2r; IQ.x = s0i + s2i; \
    RQ.z = s0r - s2r; IQ.z = s0i - s2i; \
    RQ.y = s1r + p3r; IQ.y = s1i + p3i; \
    RQ.w = s1r - p3r; IQ.w = s1i - p3i; }
    Q4I(r0, i0) Q4I(r1, i1) Q4I(r2, i2) Q4I(r3, i3)
#undef Q4I
#define TCI(CMP, C) { \
    const float w1r = K16C[C], w1i = K16S[C]; \
    const float w3r = w1r*w1r - w1i*w1i, w3i = 2.f*w1r*w1i; \
    const float m1r = r1.CMP*w3r - i1.CMP*w3i, m1i = i1.CMP*w3r + r1.CMP*w3i; \
    const float s0r = r0.CMP + m1r, s0i = i0.CMP + m1i; \
    const float s1r = r0.CMP - m1r, s1i = i0.CMP - m1i; \
    const float m3r = r3.CMP*w3r - i3.CMP*w3i, m3i = i3.CMP*w3r + r3.CMP*w3i; \
    const float s2r = r2.CMP + m3r, s2i = i2.CMP + m3i; \
    const float s3r = r2.CMP - m3r, s3i = i2.CMP - m3i; \
    const float t2r = s2r*w1r - s2i*w1i, t2i = s2i*w1r + s2r*w1i; \
    const float n3r = s3r*w1r - s3i*w1i, n3i = s3i*w1r + s3r*w1i; \
    const float t3r = -n3i, t3i = n3r; \
    r0.CMP = s0r + t2r; i0.CMP = s0i + t2i; \
    r2.CMP = s0r - t2r; i2.CMP = s0i - t2i; \
    r1.CMP = s1r + t3r; i1.CMP = s1i + t3i; \
    r3.CMP = s1r - t3r; i3.CMP = s1i - t3i; }
    TCI(x,0) TCI(y,1) TCI(z,2) TCI(w,3)
#undef TCI
    PQ4(z0, r0, i0) PQ4(z1, r1, i1) PQ4(z2, r2, i2) PQ4(z3, r3, i3)
    *(uint4*)(pc + Pb) = z0;     *(uint4*)(pc + Pb + 4) = z1;
    *(uint4*)(pc + Pb + 8) = z2; *(uint4*)(pc + Pb + 12) = z3;
}

// ---------------- Kernel A: pipelined FFT autocorrelation ----------------
// grid 512 blocks (2/CU, all resident); block 512 thr = 8 waves; each block
// processes 4 consecutive 8-series tiles with double-buffered LDS:
//   [issue loads tile i+1 -> regs] [compute tile i (wave-private)] [barrier]
//   [writeout tile i || stage-write regs -> other buffer] [barrier] swap.
__global__ __launch_bounds__(512) void fftcorr_kernel(
    const float* __restrict__ q, const float* __restrict__ k,
    float* __restrict__ corr_out, float* __restrict__ ws_mean)
{
    extern __shared__ u32 LDSU[];
    float* tabf = (float*)(LDSU + TBOU);
    const int tid = threadIdx.x;
    const int w = tid >> 6, lane = tid & 63;

    if (tid < 256) {
        float sv, cv;
        __sincosf((float)tid * (6.2831853071795865f / 1024.f), &sv, &cv);
        tabf[TPHYS(tid)] = cv;
        tabf[272 + TPHYS(tid)] = sv;
    }

    // tile decode: T in [0,2048): e-tile = T&7, h = (T>>3)&7, n = T>>6
#define TDEC(T, N_, H_, E0_) const int N_ = (T) >> 6; const int H_ = ((T) >> 3) & 7; const int E0_ = ((T) & 7) * 8;

    const int T0 = blockIdx.x * 4;

    // prologue: stage tile T0 directly into buffer 0
    {
        TDEC(T0, n, h, e0)
#pragma unroll
        for (int c = 0; c < 4; ++c) {
            const int idx = c * 512 + tid;
            const int eh = idx & 1;
            const int t  = idx >> 1;
            const size_t g = ((((size_t)n * L_SEQ + t) * NH + h) * NE) + e0 + 4 * eh;
            const float4 qv = *reinterpret_cast<const float4*>(q + g);
            const float4 kv = *reinterpret_cast<const float4*>(k + g);
            const int ph = PHYS(t);
            LDSU[(size_t)(4 * eh + 0) * PSC + ph] = PK(qv.x, kv.x);
            LDSU[(size_t)(4 * eh + 1) * PSC + ph] = PK(qv.y, kv.y);
            LDSU[(size_t)(4 * eh + 2) * PSC + ph] = PK(qv.z, kv.z);
            LDSU[(size_t)(4 * eh + 3) * PSC + ph] = PK(qv.w, kv.w);
        }
    }
    __syncthreads();

    float4 qv0, qv1, qv2, qv3, kv0, kv1, kv2, kv3;   // next-tile staging regs

#pragma unroll 1
    for (int it = 0; it < 4; ++it) {
        const int T = T0 + it;
        TDEC(T, n, h, e0)
        u32* pcu = LDSU + (size_t)(it & 1) * BUFU;         // compute buffer
        u32* psb = LDSU + (size_t)((it & 1) ^ 1) * BUFU;   // stage buffer
        const bool more = (it < 3);

        // 1. issue next tile's global loads into named registers
        if (more) {
            TDEC(T + 1, nn, nh, ne0)
#define LD(C) { const int idx = C * 512 + tid; const int eh = idx & 1; const int t = idx >> 1; \
            const size_t g = ((((size_t)nn * L_SEQ + t) * NH + nh) * NE) + ne0 + 4 * eh; \
            qv##C = *reinterpret_cast<const float4*>(q + g); \
            kv##C = *reinterpret_cast<const float4*>(k + g); }
            LD(0) LD(1) LD(2) LD(3)
#undef LD
        }

        // 2. FFT compute on pcu (wave-private plane -> no internal barriers)
        {
            u32* pc = pcu + (size_t)w * PSC;
            head4_fwd(pc, tabf, lane);
            dif_mid(pc, tabf, lane);
            tail_fused(pc, lane);
            dit_mid(pc, tabf, lane);
            head4_inv(pc, tabf, lane);
        }
        __syncthreads();   // all planes of pcu final

        // 3. writeout pcu -> global  ||  stage regs -> psb
#pragma unroll
        for (int c = 0; c < 4; ++c) {
            const int f4idx = c * 512 + tid;
            const int l  = f4idx >> 1;
            const int j4 = f4idx & 1;
            const int ph = PHYS(l);
            float4 v;
            v.x = UPK(pcu[(size_t)(4 * j4 + 0) * PSC + ph]).x;
            v.y = UPK(pcu[(size_t)(4 * j4 + 1) * PSC + ph]).x;
            v.z = UPK(pcu[(size_t)(4 * j4 + 2) * PSC + ph]).x;
            v.w = UPK(pcu[(size_t)(4 * j4 + 3) * PSC + ph]).x;
            *reinterpret_cast<float4*>(
                corr_out + ((((size_t)n * L_SEQ + l) * NH + h) * NE) + e0 + 4 * j4) = v;
            const float esum = v.x + v.y + v.z + v.w;
            const float tot = esum + __shfl_xor(esum, 1, 64);
            if ((tid & 1) == 0) atomicAdd(&ws_mean[n * L_SEQ + l], tot);
        }
        if (more) {
#define ST(C) { const int idx = C * 512 + tid; const int eh = idx & 1; const int t = idx >> 1; \
            const int ph = PHYS(t); \
            psb[(size_t)(4 * eh + 0) * PSC + ph] = PK(qv##C.x, kv##C.x); \
            psb[(size_t)(4 * eh + 1) * PSC + ph] = PK(qv##C.y, kv##C.y); \
            psb[(size_t)(4 * eh + 2) * PSC + ph] = PK(qv##C.z, kv##C.z); \
            psb[(size_t)(4 * eh + 3) * PSC + ph] = PK(qv##C.w, kv##C.w); }
            ST(0) ST(1) ST(2) ST(3)
#undef ST
        }
        __syncthreads();   // psb staged; pcu reads done (free next iter)
    }
#undef TDEC
}

// ---------------- Kernel B: top-6 lags + per-n softmax ----------------
__global__ __launch_bounds__(1024) void topk_softmax_kernel(
    const float* __restrict__ ws_mean, int* __restrict__ ws_idx,
    float* __restrict__ ws_w)
{
    __shared__ float val[1024];
    __shared__ float rv[1024];
    __shared__ int   ri[1024];
    __shared__ int   sel[TOPK];
    const int tid = threadIdx.x;

    float s = 0.f;
    for (int n = 0; n < NB; ++n) s += ws_mean[n * L_SEQ + tid];
    val[tid] = s;
    __syncthreads();

    for (int kk = 0; kk < TOPK; ++kk) {
        rv[tid] = val[tid];
        ri[tid] = tid;
        __syncthreads();
        for (int off = 512; off > 0; off >>= 1) {
            if (tid < off) {
                const float a = rv[tid], b = rv[tid + off];
                const int ia = ri[tid], ib = ri[tid + off];
                if (b > a || (b == a && ib < ia)) { rv[tid] = b; ri[tid] = ib; }
            }
            __syncthreads();
        }
        if (tid == 0) { sel[kk] = ri[0]; val[ri[0]] = -1e30f; }
        __syncthreads();
    }
    if (tid < TOPK) ws_idx[tid] = sel[tid];

    if (tid < NB) {
        float wv[TOPK];
        float m = -1e30f;
        for (int kk = 0; kk < TOPK; ++kk) {
            wv[kk] = ws_mean[tid * L_SEQ + sel[kk]] * (1.f / (NH * NE));
            m = fmaxf(m, wv[kk]);
        }
        float sum = 0.f;
        for (int kk = 0; kk < TOPK; ++kk) { wv[kk] = expf(wv[kk] - m); sum += wv[kk]; }
        const float inv = 1.f / sum;
        for (int kk = 0; kk < TOPK; ++kk) ws_w[tid * 8 + kk] = wv[kk] * inv;
    }
}

// ---------------- Kernel C: lag-gather weighted sum of v ----------------
__global__ __launch_bounds__(256) void gather_kernel(
    const float* __restrict__ v, const int* __restrict__ ws_idx,
    const float* __restrict__ ws_w, float* __restrict__ out)
{
    const int n = blockIdx.y;
    const int idx4 = blockIdx.x * 256 + threadIdx.x;
    const int l = idx4 >> 7;
    const int r = idx4 & 127;
    const float* wrow = ws_w + n * 8;

    float4 acc = make_float4(0.f, 0.f, 0.f, 0.f);
#pragma unroll
    for (int kk = 0; kk < TOPK; ++kk) {
        const int t = (l + ws_idx[kk]) & (L_SEQ - 1);
        const float4 vv = *reinterpret_cast<const float4*>(
            v + (((size_t)n * L_SEQ + t) * (NH * NE)) + r * 4);
        const float wk = wrow[kk];
        acc.x = fmaf(wk, vv.x, acc.x);
        acc.y = fmaf(wk, vv.y, acc.y);
        acc.z = fmaf(wk, vv.z, acc.z);
        acc.w = fmaf(wk, vv.w, acc.w);
    }
    *reinterpret_cast<float4*>(out + ((size_t)n * L_SEQ + l) * (NH * NE) + r * 4) = acc;
}

extern "C" void kernel_launch(void* const* d_in, const int* in_sizes, int n_in,
                              void* d_out, int out_size, void* d_ws, size_t ws_size,
                              hipStream_t stream)
{
    const float* q = (const float*)d_in[0];
    const float* k = (const float*)d_in[1];
    const float* v = (const float*)d_in[2];
    float* out = (float*)d_out;
    float* corr_out = out + (size_t)NB * L_SEQ * NH * NE;

    float* ws_mean = (float*)d_ws;                              // 32*1024 f32
    int*   ws_idx  = (int*)((char*)d_ws + 131072);              // 6 ints
    float* ws_w    = (float*)((char*)d_ws + 131072 + 256);      // 32*8 f32

    hipMemsetAsync(d_ws, 0, 131072, stream);
    fftcorr_kernel<<<dim3(512), 512, LDS_BYTES, stream>>>(q, k, corr_out, ws_mean);
    topk_softmax_kernel<<<1, 1024, 0, stream>>>(ws_mean, ws_idx, ws_w);
    gather_kernel<<<dim3(512, NB), 256, 0, stream>>>(v, ws_idx, ws_w, out);
}

// Round 17
// 178.100 us; speedup vs baseline: 1.0562x; 1.0562x over previous
//
#include <hip/hip_runtime.h>
#include <hip/hip_fp16.h>

#define L_SEQ 1024
#define NB 32
#define NH 8
#define NE 64
#define TOPK 6

typedef unsigned int u32;

// LDS geometry (round 15 best-build, reverted): 16 fp16x2-packed complex
// series planes + fp32 table. Plane: 1024 packed complex (u32), 32 groups of
// 32 at stride 36. 16*1152*4 + 544*4 = 75,904 B -> 2 blocks/CU; block = 1024
// thr = 16 waves. Rounds 10-16: seven structural variants (pass-count 7/6/5,
// VALU-pipe exchange, fp16, wide tiles, double-buffer pipeline) all land
// 149-175us -> per-wave serial-chain latency floor. This round only speeds
// the auxiliary topk kernel (wave-shuffle argmax).
#define PSC  1152                 // u32 per packed series plane
#define TBOU (16 * PSC)           // table offset (u32 units)
#define PHYS(L)  (36 * ((L) >> 5) + ((L) & 31))
#define TPHYS(E) ((E) + ((E) >> 4))
#define LDS_BYTES ((TBOU + 544) * 4)   // 75,904 B

constexpr float K16C[4] = {1.f, 0.92387953f, 0.70710678f, 0.38268343f};
constexpr float K16S[4] = {0.f, 0.38268343f, 0.70710678f, 0.92387953f};

__device__ __forceinline__ u32 PK(float r, float i) {
    union { __half2 h; u32 u; } c;
    c.h = __floats2half2_rn(r, i);
    return c.u;
}
__device__ __forceinline__ float2 UPK(u32 u) {
    union { u32 u; __half2 h; } c;
    c.u = u;
    return __half22float2(c.h);
}
#define UQ4(Z,R,I) { const float2 a_=UPK(Z.x), b_=UPK(Z.y), c_=UPK(Z.z), d_=UPK(Z.w); \
    R = make_float4(a_.x,b_.x,c_.x,d_.x); I = make_float4(a_.y,b_.y,c_.y,d_.y); }
#define PQ4(Z,R,I) { Z.x=PK(R.x,I.x); Z.y=PK(R.y,I.y); Z.z=PK(R.z,I.z); Z.w=PK(R.w,I.w); }

#define BTF4F(A,B,C,D) { \
    const float t0r = xr##A + xr##C, t0i = xi##A + xi##C; \
    const float d2r = xr##A - xr##C, d2i = xi##A - xi##C; \
    const float t2r = d2r*w1r - d2i*w1i, t2i = d2i*w1r + d2r*w1i; \
    const float t1r = xr##B + xr##D, t1i = xi##B + xi##D; \
    const float d3r = xr##B - xr##D, d3i = xi##B - xi##D; \
    const float m3r = d3r*w1r - d3i*w1i, m3i = d3i*w1r + d3r*w1i; \
    const float t3r = m3i, t3i = -m3r; \
    const float a0r = t0r + t1r, a0i = t0i + t1i; \
    const float a1r = t0r - t1r, a1i = t0i - t1i; \
    const float a2r = t2r + t3r, a2i = t2i + t3i; \
    const float a3r = t2r - t3r, a3i = t2i - t3i; \
    xr##A = a0r; xi##A = a0i; \
    xr##B = a1r*w3r - a1i*w3i; xi##B = a1i*w3r + a1r*w3i; \
    xr##C = a2r; xi##C = a2i; \
    xr##D = a3r*w3r - a3i*w3i; xi##D = a3i*w3r + a3r*w3i; }

#define BTF4I(A,B,C,D) { \
    const float m1r = xr##B*w3r - xi##B*w3i, m1i = xi##B*w3r + xr##B*w3i; \
    const float s0r = xr##A + m1r, s0i = xi##A + m1i; \
    const float s1r = xr##A - m1r, s1i = xi##A - m1i; \
    const float m3r = xr##D*w3r - xi##D*w3i, m3i = xi##D*w3r + xr##D*w3i; \
    const float s2r = xr##C + m3r, s2i = xi##C + m3i; \
    const float s3r = xr##C - m3r, s3i = xi##C - m3i; \
    const float t2r = s2r*w1r - s2i*w1i, t2i = s2i*w1r + s2r*w1i; \
    const float n3r = s3r*w1r - s3i*w1i, n3i = s3i*w1r + s3r*w1i; \
    const float t3r = -n3i, t3i = n3r; \
    xr##A = s0r + t2r; xi##A = s0i + t2i; \
    xr##C = s0r - t2r; xi##C = s0i - t2i; \
    xr##B = s1r + t3r; xi##B = s1i + t3i; \
    xr##D = s1r - t3r; xi##D = s1i - t3i; }

// ---- head4: levels 1024,512,256,128 in one pass; lane owns {lane + 64j}.
__device__ __forceinline__ void head4_fwd(u32* __restrict__ pc,
                                          const float* __restrict__ tab, int lane)
{
    const int A0 = 36 * (lane >> 5) + (lane & 31);
    const float tc = tab[TPHYS(lane)];
    const float ts = tab[272 + TPHYS(lane)];
    const float wbr = tc, wbi = -ts;
    const float w2r = wbr*wbr - wbi*wbi, w2i = 2.f*wbr*wbi;
    const float w4r = w2r*w2r - w2i*w2i, w4i = 2.f*w2r*w2i;
    const float w8r = w4r*w4r - w4i*w4i, w8i = 2.f*w4r*w4i;
#define HD(J) float xr##J, xi##J; { const float2 z_ = UPK(pc[A0 + 72*J]); xr##J = z_.x; xi##J = z_.y; }
    HD(0) HD(1) HD(2) HD(3) HD(4) HD(5) HD(6) HD(7)
    HD(8) HD(9) HD(10) HD(11) HD(12) HD(13) HD(14) HD(15)
#undef HD
#define STA(JA,JB,JC,JD,J16) { \
    const float w1r = wbr*K16C[J16] + wbi*K16S[J16]; \
    const float w1i = wbi*K16C[J16] - wbr*K16S[J16]; \
    const float w3r = w1r*w1r - w1i*w1i, w3i = 2.f*w1r*w1i; \
    BTF4F(JA,JB,JC,JD) }
    STA(0,4,8,12,0) STA(1,5,9,13,1) STA(2,6,10,14,2) STA(3,7,11,15,3)
#undef STA
    {
        const float w1r = w4r, w1i = w4i, w3r = w8r, w3i = w8i;
        BTF4F(0,1,2,3) BTF4F(4,5,6,7) BTF4F(8,9,10,11) BTF4F(12,13,14,15)
    }
#define HS(J) pc[A0 + 72*J] = PK(xr##J, xi##J);
    HS(0) HS(1) HS(2) HS(3) HS(4) HS(5) HS(6) HS(7)
    HS(8) HS(9) HS(10) HS(11) HS(12) HS(13) HS(14) HS(15)
#undef HS
}

__device__ __forceinline__ void head4_inv(u32* __restrict__ pc,
                                          const float* __restrict__ tab, int lane)
{
    const int A0 = 36 * (lane >> 5) + (lane & 31);
    const float tc = tab[TPHYS(lane)];
    const float ts = tab[272 + TPHYS(lane)];
    const float vbr = tc, vbi = ts;
    const float v2r = vbr*vbr - vbi*vbi, v2i = 2.f*vbr*vbi;
    const float v4r = v2r*v2r - v2i*v2i, v4i = 2.f*v2r*v2i;
    const float v8r = v4r*v4r - v4i*v4i, v8i = 2.f*v4r*v4i;
#define HD(J) float xr##J, xi##J; { const float2 z_ = UPK(pc[A0 + 72*J]); xr##J = z_.x; xi##J = z_.y; }
    HD(0) HD(1) HD(2) HD(3) HD(4) HD(5) HD(6) HD(7)
    HD(8) HD(9) HD(10) HD(11) HD(12) HD(13) HD(14) HD(15)
#undef HD
    {
        const float w1r = v4r, w1i = v4i, w3r = v8r, w3i = v8i;
        BTF4I(0,1,2,3) BTF4I(4,5,6,7) BTF4I(8,9,10,11) BTF4I(12,13,14,15)
    }
#define STB(JA,JB,JC,JD,J16) { \
    const float w1r = vbr*K16C[J16] - vbi*K16S[J16]; \
    const float w1i = vbi*K16C[J16] + vbr*K16S[J16]; \
    const float w3r = w1r*w1r - w1i*w1i, w3i = 2.f*w1r*w1i; \
    BTF4I(JA,JB,JC,JD) }
    STB(0,4,8,12,0) STB(1,5,9,13,1) STB(2,6,10,14,2) STB(3,7,11,15,3)
#undef STB
#define HS(J) pc[A0 + 72*J] = PK(xr##J, xi##J);
    HS(0) HS(1) HS(2) HS(3) HS(4) HS(5) HS(6) HS(7)
    HS(8) HS(9) HS(10) HS(11) HS(12) HS(13) HS(14) HS(15)
#undef HS
}

// ---- mid stage (levels 64,32): packed-quad radix-4
__device__ __forceinline__ void dif_mid(u32* __restrict__ pc,
                                        const float* __restrict__ tab, int lane)
{
    const int b0 = lane << 2;
    const int u0 = b0 & 15;
    const int Lb = ((b0 >> 4) << 6) + u0;
    const int P0 = PHYS(Lb), P1 = PHYS(Lb + 16), P2 = PHYS(Lb + 32), P3 = PHYS(Lb + 48);
    uint4 z0 = *(const uint4*)(pc + P0), z1 = *(const uint4*)(pc + P1);
    uint4 z2 = *(const uint4*)(pc + P2), z3 = *(const uint4*)(pc + P3);
    float4 r0, i0, r1, i1, r2, i2, r3, i3;
    UQ4(z0, r0, i0) UQ4(z1, r1, i1) UQ4(z2, r2, i2) UQ4(z3, r3, i3)
#define CBTF(CMP, II) { \
    const int e1 = (u0 + II) << 4; \
    const float w1c = tab[TPHYS(e1)]; \
    const float w1s = tab[272 + TPHYS(e1)]; \
    const float w3c = w1c * w1c - w1s * w1s; \
    const float w3s = 2.f * w1c * w1s; \
    const float t0r = r0.CMP + r2.CMP, t0i = i0.CMP + i2.CMP; \
    const float d2r = r0.CMP - r2.CMP, d2i = i0.CMP - i2.CMP; \
    const float t2r = d2r * w1c + d2i * w1s, t2i = d2i * w1c - d2r * w1s; \
    const float t1r = r1.CMP + r3.CMP, t1i = i1.CMP + i3.CMP; \
    const float d3r = r1.CMP - r3.CMP, d3i = i1.CMP - i3.CMP; \
    const float m3r = d3r * w1c + d3i * w1s, m3i = d3i * w1c - d3r * w1s; \
    const float t3r = m3i, t3i = -m3r; \
    const float a0r = t0r + t1r, a0i = t0i + t1i; \
    const float a1r = t0r - t1r, a1i = t0i - t1i; \
    const float a2r = t2r + t3r, a2i = t2i + t3i; \
    const float a3r = t2r - t3r, a3i = t2i - t3i; \
    r0.CMP = a0r;                     i0.CMP = a0i; \
    r1.CMP = a1r * w3c + a1i * w3s;   i1.CMP = a1i * w3c - a1r * w3s; \
    r2.CMP = a2r;                     i2.CMP = a2i; \
    r3.CMP = a3r * w3c + a3i * w3s;   i3.CMP = a3i * w3c - a3r * w3s; }
    CBTF(x, 0) CBTF(y, 1) CBTF(z, 2) CBTF(w, 3)
#undef CBTF
    PQ4(z0, r0, i0) PQ4(z1, r1, i1) PQ4(z2, r2, i2) PQ4(z3, r3, i3)
    *(uint4*)(pc + P0) = z0; *(uint4*)(pc + P1) = z1;
    *(uint4*)(pc + P2) = z2; *(uint4*)(pc + P3) = z3;
}

__device__ __forceinline__ void dit_mid(u32* __restrict__ pc,
                                        const float* __restrict__ tab, int lane)
{
    const int b0 = lane << 2;
    const int u0 = b0 & 15;
    const int Lb = ((b0 >> 4) << 6) + u0;
    const int P0 = PHYS(Lb), P1 = PHYS(Lb + 16), P2 = PHYS(Lb + 32), P3 = PHYS(Lb + 48);
    uint4 z0 = *(const uint4*)(pc + P0), z1 = *(const uint4*)(pc + P1);
    uint4 z2 = *(const uint4*)(pc + P2), z3 = *(const uint4*)(pc + P3);
    float4 r0, i0, r1, i1, r2, i2, r3, i3;
    UQ4(z0, r0, i0) UQ4(z1, r1, i1) UQ4(z2, r2, i2) UQ4(z3, r3, i3)
#define CBTI(CMP, II) { \
    const int e1 = (u0 + II) << 4; \
    const float w1c = tab[TPHYS(e1)]; \
    const float w1s = tab[272 + TPHYS(e1)]; \
    const float w3c = w1c * w1c - w1s * w1s; \
    const float w3s = 2.f * w1c * w1s; \
    const float m1r = r1.CMP * w3c - i1.CMP * w3s, m1i = i1.CMP * w3c + r1.CMP * w3s; \
    const float s0r = r0.CMP + m1r, s0i = i0.CMP + m1i; \
    const float s1r = r0.CMP - m1r, s1i = i0.CMP - m1i; \
    const float m3r = r3.CMP * w3c - i3.CMP * w3s, m3i = i3.CMP * w3c + r3.CMP * w3s; \
    const float s2r = r2.CMP + m3r, s2i = i2.CMP + m3i; \
    const float s3r = r2.CMP - m3r, s3i = i2.CMP - m3i; \
    const float p2r = s2r * w1c - s2i * w1s, p2i = s2i * w1c + s2r * w1s; \
    const float n3r = s3r * w1c - s3i * w1s, n3i = s3i * w1c + s3r * w1s; \
    const float p3r = -n3i, p3i = n3r; \
    r0.CMP = s0r + p2r; i0.CMP = s0i + p2i; \
    r2.CMP = s0r - p2r; i2.CMP = s0i - p2i; \
    r1.CMP = s1r + p3r; i1.CMP = s1i + p3i; \
    r3.CMP = s1r - p3r; i3.CMP = s1i - p3i; }
    CBTI(x, 0) CBTI(y, 1) CBTI(z, 2) CBTI(w, 3)
#undef CBTI
    PQ4(z0, r0, i0) PQ4(z1, r1, i1) PQ4(z2, r2, i2) PQ4(z3, r3, i3)
    *(uint4*)(pc + P0) = z0; *(uint4*)(pc + P1) = z1;
    *(uint4*)(pc + P2) = z2; *(uint4*)(pc + P3) = z3;
}

// ---- tail_fused: levels 16..2 | S=Q*conj(K)/1024 | levels 2..16, one trip.
__device__ __forceinline__ void tail_fused(u32* __restrict__ pc, int lane)
{
    const int Pb = PHYS(lane << 4);
    uint4 z0 = *(const uint4*)(pc + Pb),     z1 = *(const uint4*)(pc + Pb + 4);
    uint4 z2 = *(const uint4*)(pc + Pb + 8), z3 = *(const uint4*)(pc + Pb + 12);
    float4 r0, i0, r1, i1, r2, i2, r3, i3;
    UQ4(z0, r0, i0) UQ4(z1, r1, i1) UQ4(z2, r2, i2) UQ4(z3, r3, i3)
#define TCF(CMP, C) { \
    const float w1r = K16C[C], w1i = -K16S[C]; \
    const float w3r = w1r*w1r - w1i*w1i, w3i = 2.f*w1r*w1i; \
    const float t0r = r0.CMP + r2.CMP, t0i = i0.CMP + i2.CMP; \
    const float d2r = r0.CMP - r2.CMP, d2i = i0.CMP - i2.CMP; \
    const float t2r = d2r*w1r - d2i*w1i, t2i = d2i*w1r + d2r*w1i; \
    const float t1r = r1.CMP + r3.CMP, t1i = i1.CMP + i3.CMP; \
    const float d3r = r1.CMP - r3.CMP, d3i = i1.CMP - i3.CMP; \
    const float m3r = d3r*w1r - d3i*w1i, m3i = d3i*w1r + d3r*w1i; \
    const float t3r = m3i, t3i = -m3r; \
    const float a0r = t0r+t1r, a0i = t0i+t1i; \
    const float a1r = t0r-t1r, a1i = t0i-t1i; \
    const float a2r = t2r+t3r, a2i = t2i+t3i; \
    const float a3r = t2r-t3r, a3i = t2i-t3i; \
    r0.CMP = a0r; i0.CMP = a0i; \
    r1.CMP = a1r*w3r - a1i*w3i; i1.CMP = a1i*w3r + a1r*w3i; \
    r2.CMP = a2r; i2.CMP = a2i; \
    r3.CMP = a3r*w3r - a3i*w3i; i3.CMP = a3i*w3r + a3r*w3i; }
    TCF(x,0) TCF(y,1) TCF(z,2) TCF(w,3)
#undef TCF
#define Q4F(RQ, IQ) { \
    const float t0r = RQ.x + RQ.z, t0i = IQ.x + IQ.z; \
    const float t2r = RQ.x - RQ.z, t2i = IQ.x - IQ.z; \
    const float t1r = RQ.y + RQ.w, t1i = IQ.y + IQ.w; \
    const float d3r = RQ.y - RQ.w, d3i = IQ.y - IQ.w; \
    const float t3r = d3i, t3i = -d3r; \
    RQ.x = t0r + t1r; IQ.x = t0i + t1i; \
    RQ.y = t0r - t1r; IQ.y = t0i - t1i; \
    RQ.z = t2r + t3r; IQ.z = t2i + t3i; \
    RQ.w = t2r - t3r; IQ.w = t2i - t3i; }
    Q4F(r0, i0) Q4F(r1, i1) Q4F(r2, i2) Q4F(r3, i3)
#undef Q4F
    PQ4(z0, r0, i0) PQ4(z1, r1, i1) PQ4(z2, r2, i2) PQ4(z3, r3, i3)
    *(uint4*)(pc + Pb) = z0;     *(uint4*)(pc + Pb + 4) = z1;
    *(uint4*)(pc + Pb + 8) = z2; *(uint4*)(pc + Pb + 12) = z3;
#define UNP(RQ, IQ, QI, CMP, JJ) { \
    const int p  = (lane << 4) + 4*QI + JJ; \
    const int f  = (int)(__brev((unsigned)p) >> 22); \
    const int fb = (1024 - f) & 1023; \
    const int pb = (int)(__brev((unsigned)fb) >> 22); \
    const float2 b_ = UPK(pc[PHYS(pb)]); \
    const float arv = RQ.CMP, aiv = IQ.CMP; \
    const float Qr = 0.5f*(arv + b_.x), Qi = 0.5f*(aiv - b_.y); \
    const float Kr = 0.5f*(aiv + b_.y), Ki = 0.5f*(b_.x - arv); \
    RQ.CMP = (Qr*Kr + Qi*Ki) * (1.f/1024.f); \
    IQ.CMP = (Qi*Kr - Qr*Ki) * (1.f/1024.f); }
    UNP(r0,i0,0,x,0) UNP(r0,i0,0,y,1) UNP(r0,i0,0,z,2) UNP(r0,i0,0,w,3)
    UNP(r1,i1,1,x,0) UNP(r1,i1,1,y,1) UNP(r1,i1,1,z,2) UNP(r1,i1,1,w,3)
    UNP(r2,i2,2,x,0) UNP(r2,i2,2,y,1) UNP(r2,i2,2,z,2) UNP(r2,i2,2,w,3)
    UNP(r3,i3,3,x,0) UNP(r3,i3,3,y,1) UNP(r3,i3,3,z,2) UNP(r3,i3,3,w,3)
#undef UNP
#define Q4I(RQ, IQ) { \
    const float s0r = RQ.x + RQ.y, s0i = IQ.x + IQ.y; \
    const float s1r = RQ.x - RQ.y, s1i = IQ.x - IQ.y; \
    const float s2r = RQ.z + RQ.w, s2i = IQ.z + IQ.w; \
    const float s3r = RQ.z - RQ.w, s3i = IQ.z - IQ.w; \
    const float p3r = -s3i, p3i = s3r; \
    RQ.x = s0r + s2r; IQ.x = s0i + s2i; \
    RQ.z = s0r - s2r; IQ.z = s0i - s2i; \
    RQ.y = s1r + p3r; IQ.y = s1i + p3i; \
    RQ.w = s1r - p3r; IQ.w = s1i - p3i; }
    Q4I(r0, i0) Q4I(r1, i1) Q4I(r2, i2) Q4I(r3, i3)
#undef Q4I
#define TCI(CMP, C) { \
    const float w1r = K16C[C], w1i = K16S[C]; \
    const float w3r = w1r*w1r - w1i*w1i, w3i = 2.f*w1r*w1i; \
    const float m1r = r1.CMP*w3r - i1.CMP*w3i, m1i = i1.CMP*w3r + r1.CMP*w3i; \
    const float s0r = r0.CMP + m1r, s0i = i0.CMP + m1i; \
    const float s1r = r0.CMP - m1r, s1i = i0.CMP - m1i; \
    const float m3r = r3.CMP*w3r - i3.CMP*w3i, m3i = i3.CMP*w3r + r3.CMP*w3i; \
    const float s2r = r2.CMP + m3r, s2i = i2.CMP + m3i; \
    const float s3r = r2.CMP - m3r, s3i = i2.CMP - m3i; \
    const float t2r = s2r*w1r - s2i*w1i, t2i = s2i*w1r + s2r*w1i; \
    const float n3r = s3r*w1r - s3i*w1i, n3i = s3i*w1r + s3r*w1i; \
    const float t3r = -n3i, t3i = n3r; \
    r0.CMP = s0r + t2r; i0.CMP = s0i + t2i; \
    r2.CMP = s0r - t2r; i2.CMP = s0i - t2i; \
    r1.CMP = s1r + t3r; i1.CMP = s1i + t3i; \
    r3.CMP = s1r - t3r; i3.CMP = s1i - t3i; }
    TCI(x,0) TCI(y,1) TCI(z,2) TCI(w,3)
#undef TCI
    PQ4(z0, r0, i0) PQ4(z1, r1, i1) PQ4(z2, r2, i2) PQ4(z3, r3, i3)
    *(uint4*)(pc + Pb) = z0;     *(uint4*)(pc + Pb + 4) = z1;
    *(uint4*)(pc + Pb + 8) = z2; *(uint4*)(pc + Pb + 12) = z3;
}

// ---------------- Kernel A: FFT autocorrelation (round-15 best build) --------
// grid (NE/16, NH, NB) = 1024 blocks; block 1024 thr = 16 waves; 16 series,
// one per wave; 2 blocks/CU.
__global__ __launch_bounds__(1024) void fftcorr_kernel(
    const float* __restrict__ q, const float* __restrict__ k,
    float* __restrict__ corr_out, float* __restrict__ ws_mean)
{
    extern __shared__ u32 LDSU[];
    float* tabf = (float*)(LDSU + TBOU);
    const int tid = threadIdx.x;
    const int n = blockIdx.z, h = blockIdx.y, e0 = blockIdx.x * 16;

    if (tid < 256) {
        float sv, cv;
        __sincosf((float)tid * (6.2831853071795865f / 1024.f), &sv, &cv);
        tabf[TPHYS(tid)] = cv;
        tabf[272 + TPHYS(tid)] = sv;
    }

    // staging: per (t): 16 e's = 64B contiguous per array (compulsory fetch)
    {
#pragma unroll
        for (int c = 0; c < 4; ++c) {
            const int idx = c * 1024 + tid;       // 0..4095
            const int eq = idx & 3;               // which float4 of 16 e's
            const int t  = idx >> 2;
            const size_t g = ((((size_t)n * L_SEQ + t) * NH + h) * NE) + e0 + 4 * eq;
            const float4 qv = *reinterpret_cast<const float4*>(q + g);
            const float4 kv = *reinterpret_cast<const float4*>(k + g);
            const int ph = PHYS(t);
            LDSU[(size_t)(4 * eq + 0) * PSC + ph] = PK(qv.x, kv.x);
            LDSU[(size_t)(4 * eq + 1) * PSC + ph] = PK(qv.y, kv.y);
            LDSU[(size_t)(4 * eq + 2) * PSC + ph] = PK(qv.z, kv.z);
            LDSU[(size_t)(4 * eq + 3) * PSC + ph] = PK(qv.w, kv.w);
        }
    }
    __syncthreads();

    const int w = tid >> 6;      // 0..15 — wave's series plane
    const int lane = tid & 63;

    {
        u32* pc = LDSU + (size_t)w * PSC;
        head4_fwd(pc, tabf, lane);
        dif_mid(pc, tabf, lane);
        tail_fused(pc, lane);
        dit_mid(pc, tabf, lane);
        head4_inv(pc, tabf, lane);
    }
    __syncthreads();

    // writeout: float4 across 4 planes' re-halves; 64B/row global writes
    {
#pragma unroll
        for (int c = 0; c < 4; ++c) {
            const int f4idx = c * 1024 + tid;     // 0..4095
            const int l  = f4idx >> 2;
            const int j4 = f4idx & 3;
            const int ph = PHYS(l);
            float4 v;
            v.x = UPK(LDSU[(size_t)(4 * j4 + 0) * PSC + ph]).x;
            v.y = UPK(LDSU[(size_t)(4 * j4 + 1) * PSC + ph]).x;
            v.z = UPK(LDSU[(size_t)(4 * j4 + 2) * PSC + ph]).x;
            v.w = UPK(LDSU[(size_t)(4 * j4 + 3) * PSC + ph]).x;
            *reinterpret_cast<float4*>(
                corr_out + ((((size_t)n * L_SEQ + l) * NH + h) * NE) + e0 + 4 * j4) = v;
            const float esum = v.x + v.y + v.z + v.w;
            float tot = esum + __shfl_xor(esum, 1, 64);
            tot += __shfl_xor(tot, 2, 64);
            if ((tid & 3) == 0) atomicAdd(&ws_mean[n * L_SEQ + l], tot);
        }
    }
}

// ---------------- Kernel B: top-6 lags + per-n softmax (wave-shuffle) --------
// block 1024 = 16 waves. Per selection: in-wave (value,index) argmax via 6
// shfl_xor steps -> 16 wave winners in LDS -> wave 0 reduces -> 2 barriers
// per selection (was 10 barrier-levels).
__global__ __launch_bounds__(1024) void topk_softmax_kernel(
    const float* __restrict__ ws_mean, int* __restrict__ ws_idx,
    float* __restrict__ ws_w)
{
    __shared__ float val[1024];
    __shared__ float wv_val[16];
    __shared__ int   wv_idx[16];
    __shared__ int   sel[TOPK];
    const int tid = threadIdx.x;
    const int wv = tid >> 6, lane = tid & 63;

    float s = 0.f;
    for (int n = 0; n < NB; ++n) s += ws_mean[n * L_SEQ + tid];
    val[tid] = s;
    __syncthreads();

    for (int kk = 0; kk < TOPK; ++kk) {
        float v = val[tid];
        int   i = tid;
        // in-wave argmax; tie-break: lower index (jax top_k first-occurrence)
#pragma unroll
        for (int off = 1; off < 64; off <<= 1) {
            const float pv = __shfl_xor(v, off, 64);
            const int   pi = __shfl_xor(i, off, 64);
            if (pv > v || (pv == v && pi < i)) { v = pv; i = pi; }
        }
        if (lane == 0) { wv_val[wv] = v; wv_idx[wv] = i; }
        __syncthreads();
        if (tid < 64) {
            float v2 = (lane < 16) ? wv_val[lane] : -1e30f;
            int   i2 = (lane < 16) ? wv_idx[lane] : 0x7fffffff;
#pragma unroll
            for (int off = 1; off < 16; off <<= 1) {
                const float pv = __shfl_xor(v2, off, 64);
                const int   pi = __shfl_xor(i2, off, 64);
                if (pv > v2 || (pv == v2 && pi < i2)) { v2 = pv; i2 = pi; }
            }
            if (lane == 0) { sel[kk] = i2; val[i2] = -1e30f; }
        }
        __syncthreads();
    }
    if (tid < TOPK) ws_idx[tid] = sel[tid];

    if (tid < NB) {
        float wvv[TOPK];
        float m = -1e30f;
        for (int kk = 0; kk < TOPK; ++kk) {
            wvv[kk] = ws_mean[tid * L_SEQ + sel[kk]] * (1.f / (NH * NE));
            m = fmaxf(m, wvv[kk]);
        }
        float sum = 0.f;
        for (int kk = 0; kk < TOPK; ++kk) { wvv[kk] = expf(wvv[kk] - m); sum += wvv[kk]; }
        const float inv = 1.f / sum;
        for (int kk = 0; kk < TOPK; ++kk) ws_w[tid * 8 + kk] = wvv[kk] * inv;
    }
}

// ---------------- Kernel C: lag-gather weighted sum of v ----------------
__global__ __launch_bounds__(256) void gather_kernel(
    const float* __restrict__ v, const int* __restrict__ ws_idx,
    const float* __restrict__ ws_w, float* __restrict__ out)
{
    const int n = blockIdx.y;
    const int idx4 = blockIdx.x * 256 + threadIdx.x;
    const int l = idx4 >> 7;
    const int r = idx4 & 127;
    const float* wrow = ws_w + n * 8;

    float4 acc = make_float4(0.f, 0.f, 0.f, 0.f);
#pragma unroll
    for (int kk = 0; kk < TOPK; ++kk) {
        const int t = (l + ws_idx[kk]) & (L_SEQ - 1);
        const float4 vv = *reinterpret_cast<const float4*>(
            v + (((size_t)n * L_SEQ + t) * (NH * NE)) + r * 4);
        const float wk = wrow[kk];
        acc.x = fmaf(wk, vv.x, acc.x);
        acc.y = fmaf(wk, vv.y, acc.y);
        acc.z = fmaf(wk, vv.z, acc.z);
        acc.w = fmaf(wk, vv.w, acc.w);
    }
    *reinterpret_cast<float4*>(out + ((size_t)n * L_SEQ + l) * (NH * NE) + r * 4) = acc;
}

extern "C" void kernel_launch(void* const* d_in, const int* in_sizes, int n_in,
                              void* d_out, int out_size, void* d_ws, size_t ws_size,
                              hipStream_t stream)
{
    const float* q = (const float*)d_in[0];
    const float* k = (const float*)d_in[1];
    const float* v = (const float*)d_in[2];
    float* out = (float*)d_out;
    float* corr_out = out + (size_t)NB * L_SEQ * NH * NE;

    float* ws_mean = (float*)d_ws;                              // 32*1024 f32
    int*   ws_idx  = (int*)((char*)d_ws + 131072);              // 6 ints
    float* ws_w    = (float*)((char*)d_ws + 131072 + 256);      // 32*8 f32

    hipMemsetAsync(d_ws, 0, 131072, stream);
    fftcorr_kernel<<<dim3(NE / 16, NH, NB), 1024, LDS_BYTES, stream>>>(q, k, corr_out, ws_mean);
    topk_softmax_kernel<<<1, 1024, 0, stream>>>(ws_mean, ws_idx, ws_w);
    gather_kernel<<<dim3(512, NB), 256, 0, stream>>>(v, ws_idx, ws_w, out);
}